// Round 2
// baseline (414.091 us; speedup 1.0000x reference)
//
#include <hip/hip_runtime.h>

// LSS voxel pooling: N_POINTS=692736, C=64, B=4, NX=256, NY=256, NZ=1 (gz==0)
// final[b, c, 0, ix, iy] = sum over points at (ix,iy,b) of x[:, c]
// out flat: ((b*64 + c)*256 + ix)*256 + iy   (fp32, 64 MB)
//
// Strategy v3: single-pass fixed-capacity bucketing, TRANSPOSED bucket layout.
//   bucket[k][v] (k = slot, v = voxel): gather's slot-k read is
//   lane-consecutive (coalesced), and only occupied slots are fetched
//   (Poisson lambda=2.64 -> ~8 MB metadata instead of 17 MB strided).
//   Gather: ONE thread per voxel, all 64 channels in registers:
//   - no duplicate metadata reads (v2 read count/bucket twice, once per half)
//   - each x row read as 16 back-to-back float4 loads (256 B to one DRAM row)
//   - 16 outstanding loads per point = 2x the MLP of v2
//   Fill: nontemporal bucket store -> no L2 write-allocate RMW fetch.

#define NPTS   692736          // = 2706 * 256 exactly
#define CFEAT  64
#define NXV    256
#define NYV    256
#define NBAT   4
#define NVOX   (NBAT * NXV * NYV)   // 262144
#define CAP    16                   // slots per voxel; P(count>16) ~ 2e-8

typedef float f32x4 __attribute__((ext_vector_type(4)));

// ws layout (bytes):
//   [0,      1 MB)   count   (memset to 0 each call)
//   [1 MB,   +4 B)   ovf_cnt (memset to 0, same memset)
//   [1 MB+64,8 MB)   ovf pairs (v, i) — worst case NPTS entries = 5.5 MB, fits
//   [8 MB,  24 MB)   bucket[CAP][NVOX]

__device__ __forceinline__ int voxel_of(const int* __restrict__ geom, int i) {
    const int4 g = *(const int4*)(geom + (size_t)i * 4);   // gx, gy, gz(=0), gb
    return (g.w * NXV + g.x) * NYV + g.y;
}

// --- 1: bin point indices into fixed-capacity per-voxel buckets -------------
__global__ __launch_bounds__(256) void fill_kernel(
    const int* __restrict__ geom, int* __restrict__ count,
    int* __restrict__ bucket, int* __restrict__ ovf_cnt, int* __restrict__ ovf)
{
    int i = blockIdx.x * 256 + threadIdx.x;     // grid exact: 2706*256 == NPTS
    int v = voxel_of(geom, i);
    int pos = atomicAdd(&count[v], 1);
    if (pos < CAP) {
        // transposed layout + nontemporal: no write-allocate RMW in L2
        __builtin_nontemporal_store(i, bucket + (size_t)pos * NVOX + v);
    } else {                                    // essentially never taken
        int j = atomicAdd(ovf_cnt, 1);
        ovf[2 * j]     = v;
        ovf[2 * j + 1] = i;
    }
}

// --- 2: gather-sum, write directly in [B, C, X, Y] --------------------------
// One thread per voxel; 256 threads/block = one (b, ix) row of iy.
// v = (b*256 + ix)*256 + iy, lanes consecutive in iy:
//   count[v], bucket[k][v] reads coalesced; out stores 256 B bursts per c.
__global__ __launch_bounds__(256) void gather_kernel(
    const float* __restrict__ x, const int* __restrict__ count,
    const int* __restrict__ bucket, const int* __restrict__ ovf_cnt,
    const int* __restrict__ ovf, float* __restrict__ out)
{
    int v = blockIdx.x * 256 + threadIdx.x;
    int cnt = count[v];
    int n   = cnt < CAP ? cnt : CAP;

    f32x4 acc[16] = {};
    for (int k = 0; k < n; ++k) {
        int p = bucket[(size_t)k * NVOX + v];
        const f32x4* row = (const f32x4*)(x + (size_t)p * CFEAT);
        #pragma unroll
        for (int q = 0; q < 16; ++q)
            acc[q] += __builtin_nontemporal_load(row + q);
    }

    if (cnt > CAP) {                      // correctness path; never in practice
        int no = *ovf_cnt;
        for (int j = 0; j < no; ++j) {
            if (ovf[2 * j] == v) {
                int p = ovf[2 * j + 1];
                const f32x4* row = (const f32x4*)(x + (size_t)p * CFEAT);
                #pragma unroll
                for (int q = 0; q < 16; ++q)
                    acc[q] += row[q];
            }
        }
    }

    // v = (b<<16) | (ix<<8) | iy
    size_t obase = (size_t)(v >> 16) * (CFEAT * NXV * NYV)
                 + (size_t)((v >> 8) & 255) * NYV + (v & 255);
    #pragma unroll
    for (int q = 0; q < 16; ++q) {
        #pragma unroll
        for (int j = 0; j < 4; ++j)
            __builtin_nontemporal_store(acc[q][j],
                out + obase + (size_t)(q * 4 + j) * (NXV * NYV));
    }
}

extern "C" void kernel_launch(void* const* d_in, const int* in_sizes, int n_in,
                              void* d_out, int out_size, void* d_ws, size_t ws_size,
                              hipStream_t stream) {
    const float* x  = (const float*)d_in[0];   // fp32 [NPTS,64]
    const int* geom = (const int*)d_in[1];     // [NPTS,4]
    float* out      = (float*)d_out;           // fp32 [4,64,256,256]

    char* w = (char*)d_ws;
    int* count   = (int*)(w);
    int* ovf_cnt = (int*)(w + (1u << 20));
    int* ovf     = (int*)(w + (1u << 20) + 64);
    int* bucket  = (int*)(w + (8u << 20));

    // zero count + ovf_cnt in one memset
    hipMemsetAsync(w, 0, (1u << 20) + 64, stream);

    fill_kernel  <<<NPTS / 256, 256, 0, stream>>>(geom, count, bucket, ovf_cnt, ovf);
    gather_kernel<<<NVOX / 256, 256, 0, stream>>>(x, count, bucket, ovf_cnt, ovf, out);
}